// Round 12
// baseline (67.022 us; speedup 1.0000x reference)
//
#include <hip/hip_runtime.h>

namespace {

typedef short  bf16x8 __attribute__((ext_vector_type(8)));
typedef float  f32x4  __attribute__((ext_vector_type(4)));

constexpr int D = 1024;   // in_features
constexpr int O = 1024;   // out_features

// fp32 -> bf16 bits, round-to-nearest-even
__device__ __forceinline__ short f2bf(float f) {
    unsigned u = __builtin_bit_cast(unsigned, f);
    u += 0x7fffu + ((u >> 16) & 1u);
    return (short)(u >> 16);
}

__device__ __forceinline__ bf16x8 cvt8(const float4 a, const float4 b) {
    bf16x8 v;
    v[0] = f2bf(a.x); v[1] = f2bf(a.y); v[2] = f2bf(a.z); v[3] = f2bf(a.w);
    v[4] = f2bf(b.x); v[5] = f2bf(b.y); v[6] = f2bf(b.z); v[7] = f2bf(b.w);
    return v;
}

__device__ __forceinline__ float4 ld4(const float* p) {
    return *reinterpret_cast<const float4*>(p);
}

// Sub-tile-pipelined fused LoRA. 256 blocks x 512 threads (8 waves), 64 rows
// per block processed as 4 sub-tiles of 16 rows. Per sub-tile:
//   P1 (hs loads + MFMA, split-K-2) -> combine (2 barriers) -> P2 (MFMA +
//   dwordx4 stores). Stores of sub-tile i drain under P1 loads of i+1 ->
//   HBM read and write streams overlap continuously.
// Wave w: e = w&3 (expert), g = w>>2 (K-half).
//   Registers: dw slice [16 kr][512] bf16 (64 VGPR) + wt2 o-eighth (64 VGPR).
// Phase-2 computes D[o][row] = mfma(wt2_frag, low_frag) so each lane owns 4
//   consecutive o -> one float4 store per MFMA pair.
__global__ void __launch_bounds__(512, 2) lora_pipe_k(
        const float* __restrict__ hs,     // [16384][1024] f32
        const float* __restrict__ alpha,  // [4][4]
        const float* __restrict__ dw,     // [64][1024] f32  (k*16+r major)
        const float* __restrict__ uw,     // [4][1024][16] f32
        float* __restrict__ out) {        // [16384][1024] f32
    __shared__ float pacc[2][4][4][64];              // split-K partials (dbuf)
    __shared__ __align__(16) short lowb[2][16][72];  // bf16 low sub-tile (dbuf)

    const int t    = threadIdx.x;
    const int w    = t >> 6;
    const int lane = t & 63;
    const int fr   = lane & 15;
    const int kgi  = lane >> 4;         // 0..3
    const int kg   = kgi * 8;
    const int e    = w & 3;             // expert
    const int g    = w >> 2;            // K-half
    const int rowblk = blockIdx.x * 64;
    const int b      = rowblk >> 12;    // batch (blocks never straddle)

    // ---------------- prologue: weights -> registers ----------------
    // dwreg[ks] = bf16(dw[e*16+fr][g*512 + ks*32 + kg .. +8]), ks=0..15
    bf16x8 dwreg[16];
#pragma unroll
    for (int ks = 0; ks < 16; ++ks) {
        const float* sp = dw + (size_t)(e * 16 + fr) * D + g * 512 + ks * 32 + kg;
        dwreg[ks] = cvt8(ld4(sp), ld4(sp + 4));
    }
    // wreg[n*2+h] = bf16(wt2[w*128 + n*16 + fr][h*32 + kg .. +8])
    bf16x8 wreg[16];
#pragma unroll
    for (int n = 0; n < 8; ++n)
#pragma unroll
        for (int h = 0; h < 2; ++h) {
            const int kr0 = h * 32 + kg;
            const float* sp = uw + (size_t)(kr0 >> 4) * 16384
                                 + (size_t)(w * 128 + n * 16 + fr) * 16 + (kr0 & 15);
            wreg[n * 2 + h] = cvt8(ld4(sp), ld4(sp + 4));
        }
    const float sc = alpha[b * 4 + e] * 4.0f;   // NETWORK_ALPHA/RANK = 4

    // hs chunk pipeline: chunk = 2 K-steps (4 float4/lane), 2 chunks in flight
    const float* hbase = hs + (size_t)rowblk * D + g * 512 + kg;
    float4 pf0[4], pf1[4];

    // cg in [0,32): sub-tile i = cg>>3, chunk c = cg&7 (cols c*64..+64 of K-half)
    auto load_chunk = [&](int cg, float4* pf) {
        const int si = cg >> 3, c = cg & 7;
        const float* p = hbase + (size_t)(si * 16 + fr) * D + c * 64;
        pf[0] = ld4(p);      pf[1] = ld4(p + 4);
        pf[2] = ld4(p + 32); pf[3] = ld4(p + 36);
    };

    load_chunk(0, pf0);

    // ---------------- sub-tile loop ----------------
#pragma unroll 1
    for (int i = 0; i < 4; ++i) {
        // P1: acc over this wave's K-half for 16 rows x 16 kr (expert e)
        f32x4 acc = (f32x4){0.f, 0.f, 0.f, 0.f};
#pragma unroll
        for (int c = 0; c < 8; ++c) {
            float4* cur = (c & 1) ? pf1 : pf0;
            const bf16x8 av0 = cvt8(cur[0], cur[1]);
            const bf16x8 av1 = cvt8(cur[2], cur[3]);
            const int cgn = i * 8 + c + 1;
            float4* nxt = (c & 1) ? pf0 : pf1;
            if (cgn < 32) load_chunk(cgn, nxt);   // uniform branch
            acc = __builtin_amdgcn_mfma_f32_16x16x32_bf16(av0, dwreg[c * 2],     acc, 0, 0, 0);
            acc = __builtin_amdgcn_mfma_f32_16x16x32_bf16(av1, dwreg[c * 2 + 1], acc, 0, 0, 0);
        }

        const int buf = i & 1;
        if (g) {
#pragma unroll
            for (int j = 0; j < 4; ++j) pacc[buf][e][j][lane] = acc[j];
        }
        __syncthreads();
        if (!g) {
#pragma unroll
            for (int j = 0; j < 4; ++j) {
                const float s = (acc[j] + pacc[buf][e][j][lane]) * sc;
                // acc[j] <-> low[row = kgi*4+j][kr = e*16+fr]
                lowb[buf][kgi * 4 + j][e * 16 + fr] = f2bf(s);
            }
        }
        __syncthreads();

        // P2: out rows of sub-tile i, cols w*128..+128.
        // Transposed MFMA: D[o][row]; lane fr = row, (kgi*4+j) = o-offset.
        const bf16x8 pa0 = *reinterpret_cast<const bf16x8*>(&lowb[buf][fr][kg]);
        const bf16x8 pa1 = *reinterpret_cast<const bf16x8*>(&lowb[buf][fr][32 + kg]);
        float* op = out + (size_t)(rowblk + i * 16 + fr) * O + w * 128;
#pragma unroll
        for (int n = 0; n < 8; ++n) {
            f32x4 c2 = (f32x4){0.f, 0.f, 0.f, 0.f};
            c2 = __builtin_amdgcn_mfma_f32_16x16x32_bf16(wreg[n * 2],     pa0, c2, 0, 0, 0);
            c2 = __builtin_amdgcn_mfma_f32_16x16x32_bf16(wreg[n * 2 + 1], pa1, c2, 0, 0, 0);
            float4 vs = make_float4(c2[0], c2[1], c2[2], c2[3]);
            *reinterpret_cast<float4*>(op + n * 16 + kgi * 4) = vs;
        }
        // stores drain while next sub-tile's P1 loads/compute run
    }
}

} // namespace

extern "C" void kernel_launch(void* const* d_in, const int* in_sizes, int n_in,
                              void* d_out, int out_size, void* d_ws, size_t ws_size,
                              hipStream_t stream) {
    const float* hs    = (const float*)d_in[0];  // [4,4096,1024]
    const float* alpha = (const float*)d_in[1];  // [4,4]
    const float* dw    = (const float*)d_in[2];  // [4,16,1024]
    const float* uw    = (const float*)d_in[3];  // [4,1024,16]
    float* outp = (float*)d_out;

    hipLaunchKernelGGL(lora_pipe_k, dim3(256), dim3(512), 0, stream,
                       hs, alpha, dw, uw, outp);
}

// Round 15
// 50.147 us; speedup vs baseline: 1.3365x; 1.3365x over previous
//
#include <hip/hip_runtime.h>

namespace {

typedef short  bf16x8 __attribute__((ext_vector_type(8)));
typedef float  f32x4  __attribute__((ext_vector_type(4)));

constexpr int D = 1024;   // in_features
constexpr int O = 1024;   // out_features

// fp32 -> bf16 bits, round-to-nearest-even
__device__ __forceinline__ short f2bf(float f) {
    unsigned u = __builtin_bit_cast(unsigned, f);
    u += 0x7fffu + ((u >> 16) & 1u);
    return (short)(u >> 16);
}

__device__ __forceinline__ bf16x8 cvt8(const float4 a, const float4 b) {
    bf16x8 v;
    v[0] = f2bf(a.x); v[1] = f2bf(a.y); v[2] = f2bf(a.z); v[3] = f2bf(a.w);
    v[4] = f2bf(b.x); v[5] = f2bf(b.y); v[6] = f2bf(b.z); v[7] = f2bf(b.w);
    return v;
}

__device__ __forceinline__ float4 ld4(const float* p) {
    return *reinterpret_cast<const float4*>(p);
}

struct StageRegs { float4 a[4]; float4 b[4]; };

__device__ __forceinline__ void issue_dw(const float* __restrict__ dw, int c, int t,
                                         StageRegs& r) {
#pragma unroll
    for (int i = 0; i < 4; ++i) {
        const int e = i * 512 + t, kr = e >> 5, cc = e & 31;
        const float* sp = dw + (size_t)kr * D + c * 256 + cc * 8;
        r.a[i] = ld4(sp);
        r.b[i] = ld4(sp + 4);
    }
}
__device__ __forceinline__ void write_p1(short* buf, int t, const StageRegs& r) {
#pragma unroll
    for (int i = 0; i < 4; ++i) {
        const int e = i * 512 + t, kr = e >> 5, cc = e & 31;
        *reinterpret_cast<bf16x8*>(&buf[kr * 264 + cc * 8]) = cvt8(r.a[i], r.b[i]);
    }
}

// ---------------- Kernel A: low = bf16(alpha*4 * hs @ dw^T) ----------------
// 256 blocks x 512 threads (8 waves), 64 rows/block. R9 phase-1 verbatim:
// dw LDS double-buffer, hs prefetched one chunk ahead in regs, split-K-2
// combine via pacc. Combine writes bf16 low tile to GLOBAL (2 MB, L2).
__global__ void __launch_bounds__(512) lora_low_k(
        const float* __restrict__ hs,     // [16384][1024] f32
        const float* __restrict__ alpha,  // [4][4]
        const float* __restrict__ dw,     // [64][1024] f32  (k*16+r major)
        short* __restrict__ lowg) {       // [16384][64] bf16 out
    __shared__ __align__(16) short bs[2][64 * 264];  // 67.6 KB dw chunks
    __shared__ float pacc[4][16][64];                // 16 KB split-K partials

    const int t    = threadIdx.x;
    const int w    = t >> 6;
    const int lane = t & 63;
    const int fr   = lane & 15;
    const int kgi  = lane >> 4;
    const int kg   = kgi * 8;
    const int rt   = w >> 1;            // row-tile 0..3
    const int kh   = w & 1;             // K-half
    const int rowblk = blockIdx.x * 64;
    const int b      = rowblk >> 12;    // batch (blocks never straddle)
    const int myrow  = rowblk + rt * 16 + fr;
    const float* apb = hs + (size_t)myrow * D + kh * 128 + kg;

    StageRegs rg;
    issue_dw(dw, 0, t, rg);

    float4 pf[8];                                  // hs chunk-0 prefetch
#pragma unroll
    for (int ks = 0; ks < 4; ++ks) {
        pf[2 * ks]     = ld4(apb + ks * 32);
        pf[2 * ks + 1] = ld4(apb + ks * 32 + 4);
    }

    write_p1(&bs[0][0], t, rg);
    __syncthreads();

    f32x4 acc[4];
#pragma unroll
    for (int nt = 0; nt < 4; ++nt) acc[nt] = (f32x4){0.f, 0.f, 0.f, 0.f};

#pragma unroll
    for (int c = 0; c < 4; ++c) {
        bf16x8 av[4];
#pragma unroll
        for (int ks = 0; ks < 4; ++ks) av[ks] = cvt8(pf[2 * ks], pf[2 * ks + 1]);

        if (c < 3) {
            const float* ap = apb + (c + 1) * 256;
#pragma unroll
            for (int ks = 0; ks < 4; ++ks) {
                pf[2 * ks]     = ld4(ap + ks * 32);
                pf[2 * ks + 1] = ld4(ap + ks * 32 + 4);
            }
            issue_dw(dw, c + 1, t, rg);
        }

#pragma unroll
        for (int ks = 0; ks < 4; ++ks)
#pragma unroll
            for (int nt = 0; nt < 4; ++nt) {
                const bf16x8 bv = *reinterpret_cast<const bf16x8*>(
                    &bs[c & 1][(nt * 16 + fr) * 264 + kh * 128 + ks * 32 + kg]);
                acc[nt] = __builtin_amdgcn_mfma_f32_16x16x32_bf16(av[ks], bv, acc[nt], 0, 0, 0);
            }

        if (c < 3) {
            write_p1(&bs[(c + 1) & 1][0], t, rg);
            __syncthreads();
        }
    }

    // split-K combine; scale by alpha*4; write bf16 low to global
    if (kh) {
#pragma unroll
        for (int nt = 0; nt < 4; ++nt)
#pragma unroll
            for (int j = 0; j < 4; ++j)
                pacc[rt][nt * 4 + j][lane] = acc[nt][j];
    }
    __syncthreads();
    if (!kh) {
#pragma unroll
        for (int nt = 0; nt < 4; ++nt) {
            const float sc = alpha[b * 4 + nt] * 4.0f;   // NETWORK_ALPHA/RANK = 4
#pragma unroll
            for (int j = 0; j < 4; ++j) {
                const float v = (acc[nt][j] + pacc[rt][nt * 4 + j][lane]) * sc;
                // D-frag: row = kgi*4+j (hs row), col = nt*16+fr (kr)
                lowg[(size_t)(rowblk + rt * 16 + kgi * 4 + j) * 64 + nt * 16 + fr] = f2bf(v);
            }
        }
    }
}

// ---------------- Kernel B: out = low @ wt2^T ----------------
// 1024 blocks x 256 threads (4 waves), 16 rows/block, wave w = o-quarter
// (cols w*256..+256) with wt2 quarter in 128 VGPR. Zero LDS, zero barriers.
// Transposed MFMA (verified in R12): D[o][row]; lane fr = out row,
// kgi*4+j = o-offset -> one float4 store per MFMA pair.
__global__ void __launch_bounds__(256) lora_up_k(
        const short* __restrict__ lowg,   // [16384][64] bf16
        const float* __restrict__ uw,     // [4][1024][16] f32
        float* __restrict__ out) {        // [16384][1024] f32
    const int t    = threadIdx.x;
    const int w    = t >> 6;            // o-quarter
    const int lane = t & 63;
    const int fr   = lane & 15;
    const int kgi  = lane >> 4;
    const int kg   = kgi * 8;
    const int row0 = blockIdx.x * 16;

    // wreg[n2*2+h] = bf16(wt2[w*256 + n2*16 + fr][h*32 + kg .. +8])
    bf16x8 wreg[32];
#pragma unroll
    for (int n2 = 0; n2 < 16; ++n2)
#pragma unroll
        for (int h = 0; h < 2; ++h) {
            const int kr0 = h * 32 + kg;
            const float* sp = uw + (size_t)(kr0 >> 4) * 16384
                                 + (size_t)(w * 256 + n2 * 16 + fr) * 16 + (kr0 & 15);
            wreg[n2 * 2 + h] = cvt8(ld4(sp), ld4(sp + 4));
        }

    const short* lp = lowg + (size_t)(row0 + fr) * 64;
    const bf16x8 pa0 = *reinterpret_cast<const bf16x8*>(lp + kg);
    const bf16x8 pa1 = *reinterpret_cast<const bf16x8*>(lp + 32 + kg);

    float* op = out + (size_t)(row0 + fr) * O + w * 256;
#pragma unroll
    for (int n2 = 0; n2 < 16; ++n2) {
        f32x4 c2 = (f32x4){0.f, 0.f, 0.f, 0.f};
        c2 = __builtin_amdgcn_mfma_f32_16x16x32_bf16(wreg[n2 * 2],     pa0, c2, 0, 0, 0);
        c2 = __builtin_amdgcn_mfma_f32_16x16x32_bf16(wreg[n2 * 2 + 1], pa1, c2, 0, 0, 0);
        const float4 vs = make_float4(c2[0], c2[1], c2[2], c2[3]);
        *reinterpret_cast<float4*>(op + n2 * 16 + kgi * 4) = vs;
    }
}

} // namespace

extern "C" void kernel_launch(void* const* d_in, const int* in_sizes, int n_in,
                              void* d_out, int out_size, void* d_ws, size_t ws_size,
                              hipStream_t stream) {
    const float* hs    = (const float*)d_in[0];  // [4,4096,1024]
    const float* alpha = (const float*)d_in[1];  // [4,4]
    const float* dw    = (const float*)d_in[2];  // [4,16,1024]
    const float* uw    = (const float*)d_in[3];  // [4,1024,16]
    short* lowg = (short*)d_ws;                  // [16384][64] bf16 = 2 MB
    float* outp = (float*)d_out;

    hipLaunchKernelGGL(lora_low_k, dim3(256),  dim3(512), 0, stream, hs, alpha, dw, lowg);
    hipLaunchKernelGGL(lora_up_k,  dim3(1024), dim3(256), 0, stream, lowg, uw, outp);
}

// Round 16
// 40.043 us; speedup vs baseline: 1.6738x; 1.2523x over previous
//
#include <hip/hip_runtime.h>

namespace {

typedef short  bf16x8 __attribute__((ext_vector_type(8)));
typedef float  f32x4  __attribute__((ext_vector_type(4)));

constexpr int D = 1024;   // in_features
constexpr int O = 1024;   // out_features

// fp32 -> bf16 bits, round-to-nearest-even
__device__ __forceinline__ short f2bf(float f) {
    unsigned u = __builtin_bit_cast(unsigned, f);
    u += 0x7fffu + ((u >> 16) & 1u);
    return (short)(u >> 16);
}

__device__ __forceinline__ bf16x8 cvt8(const float4 a, const float4 b) {
    bf16x8 v;
    v[0] = f2bf(a.x); v[1] = f2bf(a.y); v[2] = f2bf(a.z); v[3] = f2bf(a.w);
    v[4] = f2bf(b.x); v[5] = f2bf(b.y); v[6] = f2bf(b.z); v[7] = f2bf(b.w);
    return v;
}

__device__ __forceinline__ float4 ld4(const float* p) {
    return *reinterpret_cast<const float4*>(p);
}

struct StageRegs { float4 a[4]; float4 b[4]; };

__device__ __forceinline__ void issue_dw(const float* __restrict__ dw, int c, int t,
                                         StageRegs& r) {
#pragma unroll
    for (int i = 0; i < 4; ++i) {
        const int e = i * 512 + t, kr = e >> 5, cc = e & 31;
        const float* sp = dw + (size_t)kr * D + c * 256 + cc * 8;
        r.a[i] = ld4(sp);
        r.b[i] = ld4(sp + 4);
    }
}
__device__ __forceinline__ void write_p1(short* buf, int t, const StageRegs& r) {
#pragma unroll
    for (int i = 0; i < 4; ++i) {
        const int e = i * 512 + t, kr = e >> 5, cc = e & 31;
        *reinterpret_cast<bf16x8*>(&buf[kr * 264 + cc * 8]) = cvt8(r.a[i], r.b[i]);
    }
}

// ---------------- Kernel A: low = bf16(alpha*4 * hs @ dw^T) ----------------
// UNCHANGED from R15 (measured ~6.7 us, ~5.2 TB/s read — near roofline).
__global__ void __launch_bounds__(512) lora_low_k(
        const float* __restrict__ hs,     // [16384][1024] f32
        const float* __restrict__ alpha,  // [4][4]
        const float* __restrict__ dw,     // [64][1024] f32  (k*16+r major)
        short* __restrict__ lowg) {       // [16384][64] bf16 out
    __shared__ __align__(16) short bs[2][64 * 264];  // 67.6 KB dw chunks
    __shared__ float pacc[4][16][64];                // 16 KB split-K partials

    const int t    = threadIdx.x;
    const int w    = t >> 6;
    const int lane = t & 63;
    const int fr   = lane & 15;
    const int kgi  = lane >> 4;
    const int kg   = kgi * 8;
    const int rt   = w >> 1;            // row-tile 0..3
    const int kh   = w & 1;             // K-half
    const int rowblk = blockIdx.x * 64;
    const int b      = rowblk >> 12;    // batch (blocks never straddle)
    const int myrow  = rowblk + rt * 16 + fr;
    const float* apb = hs + (size_t)myrow * D + kh * 128 + kg;

    StageRegs rg;
    issue_dw(dw, 0, t, rg);

    float4 pf[8];                                  // hs chunk-0 prefetch
#pragma unroll
    for (int ks = 0; ks < 4; ++ks) {
        pf[2 * ks]     = ld4(apb + ks * 32);
        pf[2 * ks + 1] = ld4(apb + ks * 32 + 4);
    }

    write_p1(&bs[0][0], t, rg);
    __syncthreads();

    f32x4 acc[4];
#pragma unroll
    for (int nt = 0; nt < 4; ++nt) acc[nt] = (f32x4){0.f, 0.f, 0.f, 0.f};

#pragma unroll
    for (int c = 0; c < 4; ++c) {
        bf16x8 av[4];
#pragma unroll
        for (int ks = 0; ks < 4; ++ks) av[ks] = cvt8(pf[2 * ks], pf[2 * ks + 1]);

        if (c < 3) {
            const float* ap = apb + (c + 1) * 256;
#pragma unroll
            for (int ks = 0; ks < 4; ++ks) {
                pf[2 * ks]     = ld4(ap + ks * 32);
                pf[2 * ks + 1] = ld4(ap + ks * 32 + 4);
            }
            issue_dw(dw, c + 1, t, rg);
        }

#pragma unroll
        for (int ks = 0; ks < 4; ++ks)
#pragma unroll
            for (int nt = 0; nt < 4; ++nt) {
                const bf16x8 bv = *reinterpret_cast<const bf16x8*>(
                    &bs[c & 1][(nt * 16 + fr) * 264 + kh * 128 + ks * 32 + kg]);
                acc[nt] = __builtin_amdgcn_mfma_f32_16x16x32_bf16(av[ks], bv, acc[nt], 0, 0, 0);
            }

        if (c < 3) {
            write_p1(&bs[(c + 1) & 1][0], t, rg);
            __syncthreads();
        }
    }

    // split-K combine; scale by alpha*4; write bf16 low to global
    if (kh) {
#pragma unroll
        for (int nt = 0; nt < 4; ++nt)
#pragma unroll
            for (int j = 0; j < 4; ++j)
                pacc[rt][nt * 4 + j][lane] = acc[nt][j];
    }
    __syncthreads();
    if (!kh) {
#pragma unroll
        for (int nt = 0; nt < 4; ++nt) {
            const float sc = alpha[b * 4 + nt] * 4.0f;   // NETWORK_ALPHA/RANK = 4
#pragma unroll
            for (int j = 0; j < 4; ++j) {
                const float v = (acc[nt][j] + pacc[rt][nt * 4 + j][lane]) * sc;
                // D-frag: row = kgi*4+j (hs row), col = nt*16+fr (kr)
                lowg[(size_t)(rowblk + rt * 16 + kgi * 4 + j) * 64 + nt * 16 + fr] = f2bf(v);
            }
        }
    }
}

// ---------------- Kernel B: out = low @ wt2^T (coalesced stores) ----------------
// 512 blocks x 256 threads (4 waves), 32 rows/block (2 tiles of 16), wave w =
// o-quarter with wt2 quarter in 128 VGPR. Per tile: 32 MFMA (transposed,
// D[o][row]) -> per-wave-private LDS transpose -> 16 x 1KB-contiguous
// float4 row stores (64 lanes x 16 B consecutive). NO __syncthreads at all;
// wave-local lgkmcnt(0) orders ds_write -> ds_read.
__global__ void __launch_bounds__(256) lora_up_k(
        const short* __restrict__ lowg,   // [16384][64] bf16
        const float* __restrict__ uw,     // [4][1024][16] f32
        float* __restrict__ out) {        // [16384][1024] f32
    __shared__ __align__(16) float lbuf[4][16 * 260];   // per-wave 16.6 KB, total 66.6 KB

    const int t    = threadIdx.x;
    const int w    = t >> 6;            // o-quarter
    const int lane = t & 63;
    const int fr   = lane & 15;
    const int kgi  = lane >> 4;
    const int kg   = kgi * 8;
    const int row0 = blockIdx.x * 32;

    // low fragments for both tiles (L2-resident lowg; issue before weights)
    const short* lp0 = lowg + (size_t)(row0 + fr) * 64;
    const short* lp1 = lowg + (size_t)(row0 + 16 + fr) * 64;
    const bf16x8 paA0 = *reinterpret_cast<const bf16x8*>(lp0 + kg);
    const bf16x8 paA1 = *reinterpret_cast<const bf16x8*>(lp0 + 32 + kg);
    const bf16x8 paB0 = *reinterpret_cast<const bf16x8*>(lp1 + kg);
    const bf16x8 paB1 = *reinterpret_cast<const bf16x8*>(lp1 + 32 + kg);

    // wreg[n2*2+h] = bf16(wt2[w*256 + n2*16 + fr][h*32 + kg .. +8])
    bf16x8 wreg[32];
#pragma unroll
    for (int n2 = 0; n2 < 16; ++n2)
#pragma unroll
        for (int h = 0; h < 2; ++h) {
            const int kr0 = h * 32 + kg;
            const float* sp = uw + (size_t)(kr0 >> 4) * 16384
                                 + (size_t)(w * 256 + n2 * 16 + fr) * 16 + (kr0 & 15);
            wreg[n2 * 2 + h] = cvt8(ld4(sp), ld4(sp + 4));
        }

    float* lb = &lbuf[w][0];

#pragma unroll
    for (int tile = 0; tile < 2; ++tile) {
        const bf16x8 pa0 = tile ? paB0 : paA0;
        const bf16x8 pa1 = tile ? paB1 : paA1;

        // MFMA + LDS transpose write: c2[j] = out[row0+t16+fr][w*256+n2*16+kgi*4+j]
#pragma unroll
        for (int n2 = 0; n2 < 16; ++n2) {
            f32x4 c2 = (f32x4){0.f, 0.f, 0.f, 0.f};
            c2 = __builtin_amdgcn_mfma_f32_16x16x32_bf16(wreg[n2 * 2],     pa0, c2, 0, 0, 0);
            c2 = __builtin_amdgcn_mfma_f32_16x16x32_bf16(wreg[n2 * 2 + 1], pa1, c2, 0, 0, 0);
            *reinterpret_cast<float4*>(lb + fr * 260 + n2 * 16 + kgi * 4) =
                make_float4(c2[0], c2[1], c2[2], c2[3]);
        }

        // all wave-private ds_writes complete before cross-lane ds_reads
        asm volatile("s_waitcnt lgkmcnt(0)" ::: "memory");

        // coalesced row stores: 64 lanes x 16 B = 1 KB contiguous per row
        float* ob = out + (size_t)(row0 + tile * 16) * O + w * 256;
#pragma unroll
        for (int r = 0; r < 16; ++r) {
            const float4 v = *reinterpret_cast<const float4*>(lb + r * 260 + lane * 4);
            *reinterpret_cast<float4*>(ob + (size_t)r * O + lane * 4) = v;
        }

        if (tile == 0)  // lbuf reuse: reads of tile 0 done before tile-1 writes (in-order DS)
            asm volatile("s_waitcnt lgkmcnt(0)" ::: "memory");
    }
}

} // namespace

extern "C" void kernel_launch(void* const* d_in, const int* in_sizes, int n_in,
                              void* d_out, int out_size, void* d_ws, size_t ws_size,
                              hipStream_t stream) {
    const float* hs    = (const float*)d_in[0];  // [4,4096,1024]
    const float* alpha = (const float*)d_in[1];  // [4,4]
    const float* dw    = (const float*)d_in[2];  // [4,16,1024]
    const float* uw    = (const float*)d_in[3];  // [4,1024,16]
    short* lowg = (short*)d_ws;                  // [16384][64] bf16 = 2 MB
    float* outp = (float*)d_out;

    hipLaunchKernelGGL(lora_low_k, dim3(256), dim3(512), 0, stream, hs, alpha, dw, lowg);
    hipLaunchKernelGGL(lora_up_k,  dim3(512), dim3(256), 0, stream, lowg, uw, outp);
}

// Round 17
// 37.011 us; speedup vs baseline: 1.8108x; 1.0819x over previous
//
#include <hip/hip_runtime.h>

namespace {

typedef short  bf16x8 __attribute__((ext_vector_type(8)));
typedef float  f32x4  __attribute__((ext_vector_type(4)));

constexpr int D = 1024;   // in_features
constexpr int O = 1024;   // out_features

// fp32 -> bf16 bits, round-to-nearest-even
__device__ __forceinline__ short f2bf(float f) {
    unsigned u = __builtin_bit_cast(unsigned, f);
    u += 0x7fffu + ((u >> 16) & 1u);
    return (short)(u >> 16);
}

__device__ __forceinline__ bf16x8 cvt8(const float4 a, const float4 b) {
    bf16x8 v;
    v[0] = f2bf(a.x); v[1] = f2bf(a.y); v[2] = f2bf(a.z); v[3] = f2bf(a.w);
    v[4] = f2bf(b.x); v[5] = f2bf(b.y); v[6] = f2bf(b.z); v[7] = f2bf(b.w);
    return v;
}

__device__ __forceinline__ float4 ld4(const float* p) {
    return *reinterpret_cast<const float4*>(p);
}

struct StageRegs { float4 a[4]; float4 b[4]; };

__device__ __forceinline__ void issue_dw(const float* __restrict__ dw, int c, int t,
                                         StageRegs& r) {
#pragma unroll
    for (int i = 0; i < 4; ++i) {
        const int e = i * 512 + t, kr = e >> 5, cc = e & 31;
        const float* sp = dw + (size_t)kr * D + c * 256 + cc * 8;
        r.a[i] = ld4(sp);
        r.b[i] = ld4(sp + 4);
    }
}
__device__ __forceinline__ void write_p1(short* buf, int t, const StageRegs& r) {
#pragma unroll
    for (int i = 0; i < 4; ++i) {
        const int e = i * 512 + t, kr = e >> 5, cc = e & 31;
        *reinterpret_cast<bf16x8*>(&buf[kr * 264 + cc * 8]) = cvt8(r.a[i], r.b[i]);
    }
}

// ---------------- Kernel A: low = bf16(alpha*4 * hs @ dw^T) ----------------
// UNCHANGED (measured ~6.7 us — L3-fed read stream near its ceiling).
__global__ void __launch_bounds__(512) lora_low_k(
        const float* __restrict__ hs,     // [16384][1024] f32
        const float* __restrict__ alpha,  // [4][4]
        const float* __restrict__ dw,     // [64][1024] f32  (k*16+r major)
        short* __restrict__ lowg) {       // [16384][64] bf16 out
    __shared__ __align__(16) short bs[2][64 * 264];  // 67.6 KB dw chunks
    __shared__ float pacc[4][16][64];                // 16 KB split-K partials

    const int t    = threadIdx.x;
    const int w    = t >> 6;
    const int lane = t & 63;
    const int fr   = lane & 15;
    const int kgi  = lane >> 4;
    const int kg   = kgi * 8;
    const int rt   = w >> 1;            // row-tile 0..3
    const int kh   = w & 1;             // K-half
    const int rowblk = blockIdx.x * 64;
    const int b      = rowblk >> 12;    // batch (blocks never straddle)
    const int myrow  = rowblk + rt * 16 + fr;
    const float* apb = hs + (size_t)myrow * D + kh * 128 + kg;

    StageRegs rg;
    issue_dw(dw, 0, t, rg);

    float4 pf[8];                                  // hs chunk-0 prefetch
#pragma unroll
    for (int ks = 0; ks < 4; ++ks) {
        pf[2 * ks]     = ld4(apb + ks * 32);
        pf[2 * ks + 1] = ld4(apb + ks * 32 + 4);
    }

    write_p1(&bs[0][0], t, rg);
    __syncthreads();

    f32x4 acc[4];
#pragma unroll
    for (int nt = 0; nt < 4; ++nt) acc[nt] = (f32x4){0.f, 0.f, 0.f, 0.f};

#pragma unroll
    for (int c = 0; c < 4; ++c) {
        bf16x8 av[4];
#pragma unroll
        for (int ks = 0; ks < 4; ++ks) av[ks] = cvt8(pf[2 * ks], pf[2 * ks + 1]);

        if (c < 3) {
            const float* ap = apb + (c + 1) * 256;
#pragma unroll
            for (int ks = 0; ks < 4; ++ks) {
                pf[2 * ks]     = ld4(ap + ks * 32);
                pf[2 * ks + 1] = ld4(ap + ks * 32 + 4);
            }
            issue_dw(dw, c + 1, t, rg);
        }

#pragma unroll
        for (int ks = 0; ks < 4; ++ks)
#pragma unroll
            for (int nt = 0; nt < 4; ++nt) {
                const bf16x8 bv = *reinterpret_cast<const bf16x8*>(
                    &bs[c & 1][(nt * 16 + fr) * 264 + kh * 128 + ks * 32 + kg]);
                acc[nt] = __builtin_amdgcn_mfma_f32_16x16x32_bf16(av[ks], bv, acc[nt], 0, 0, 0);
            }

        if (c < 3) {
            write_p1(&bs[(c + 1) & 1][0], t, rg);
            __syncthreads();
        }
    }

    // split-K combine; scale by alpha*4; write bf16 low to global
    if (kh) {
#pragma unroll
        for (int nt = 0; nt < 4; ++nt)
#pragma unroll
            for (int j = 0; j < 4; ++j)
                pacc[rt][nt * 4 + j][lane] = acc[nt][j];
    }
    __syncthreads();
    if (!kh) {
#pragma unroll
        for (int nt = 0; nt < 4; ++nt) {
            const float sc = alpha[b * 4 + nt] * 4.0f;   // NETWORK_ALPHA/RANK = 4
#pragma unroll
            for (int j = 0; j < 4; ++j) {
                const float v = (acc[nt][j] + pacc[rt][nt * 4 + j][lane]) * sc;
                lowg[(size_t)(rowblk + rt * 16 + kgi * 4 + j) * 64 + nt * 16 + fr] = f2bf(v);
            }
        }
    }
}

// ---------------- Kernel B: out = low @ wt2^T (contiguous store bursts) ----------------
// 256 blocks x 512 threads (8 waves), 64 rows/block as 4 tiles of 16 rows.
// Per tile: each wave MFMAs its o-eighth (wreg in regs) into a block-wide
// double-buffered LDS tile [16][1026]; raw lgkmcnt(0)+s_barrier (NO vmcnt
// drain -> stores flow across barriers); then wave w stores rows w*2,w*2+1
// = 8 KB fully CONTIGUOUS per burst (8 x 1KB dwordx4 back-to-back).
__global__ void __launch_bounds__(512) lora_up_k(
        const short* __restrict__ lowg,   // [16384][64] bf16
        const float* __restrict__ uw,     // [4][1024][16] f32
        float* __restrict__ out) {        // [16384][1024] f32
    __shared__ __align__(16) float lbuf[2][16][1026];   // 2 x 65.7 KB

    const int t    = threadIdx.x;
    const int w    = t >> 6;            // o-eighth (cols w*128..+128)
    const int lane = t & 63;
    const int fr   = lane & 15;
    const int kgi  = lane >> 4;
    const int kg   = kgi * 8;
    const int row0 = blockIdx.x * 64;

    // low fragments for all 4 tiles (L2-resident, issue first)
    bf16x8 paT[4][2];
#pragma unroll
    for (int i = 0; i < 4; ++i) {
        const short* lp = lowg + (size_t)(row0 + i * 16 + fr) * 64;
        paT[i][0] = *reinterpret_cast<const bf16x8*>(lp + kg);
        paT[i][1] = *reinterpret_cast<const bf16x8*>(lp + 32 + kg);
    }

    // wreg[n2*2+h] = bf16(wt2[w*128 + n2*16 + fr][h*32 + kg .. +8])
    bf16x8 wreg[16];
#pragma unroll
    for (int n2 = 0; n2 < 8; ++n2)
#pragma unroll
        for (int h = 0; h < 2; ++h) {
            const int kr0 = h * 32 + kg;
            const float* sp = uw + (size_t)(kr0 >> 4) * 16384
                                 + (size_t)(w * 128 + n2 * 16 + fr) * 16 + (kr0 & 15);
            wreg[n2 * 2 + h] = cvt8(ld4(sp), ld4(sp + 4));
        }

#pragma unroll
    for (int i = 0; i < 4; ++i) {
        const int buf = i & 1;
        // MFMA o-eighth into LDS: lane holds out[row=fr][o=w*128+n2*16+kgi*4+j]
#pragma unroll
        for (int n2 = 0; n2 < 8; ++n2) {
            f32x4 c2 = (f32x4){0.f, 0.f, 0.f, 0.f};
            c2 = __builtin_amdgcn_mfma_f32_16x16x32_bf16(wreg[n2 * 2],     paT[i][0], c2, 0, 0, 0);
            c2 = __builtin_amdgcn_mfma_f32_16x16x32_bf16(wreg[n2 * 2 + 1], paT[i][1], c2, 0, 0, 0);
            *reinterpret_cast<float4*>(&lbuf[buf][fr][w * 128 + n2 * 16 + kgi * 4]) =
                make_float4(c2[0], c2[1], c2[2], c2[3]);
        }

        // ds_writes (and prior tile's ds_reads) complete, then barrier.
        // NO vmcnt drain: the store stream keeps flowing across barriers.
        asm volatile("s_waitcnt lgkmcnt(0)" ::: "memory");
        __builtin_amdgcn_s_barrier();

        // contiguous burst: wave w stores rows w*2, w*2+1 (8 KB linear)
        float* ob = out + (size_t)(row0 + i * 16 + w * 2) * O;
        const float* lr = &lbuf[buf][w * 2][0];
#pragma unroll
        for (int r2 = 0; r2 < 2; ++r2)
#pragma unroll
            for (int c = 0; c < 4; ++c) {
                const float4 v = *reinterpret_cast<const float4*>(
                    lr + r2 * 1026 + c * 256 + lane * 4);
                *reinterpret_cast<float4*>(ob + (size_t)r2 * O + c * 256 + lane * 4) = v;
            }
    }
}

} // namespace

extern "C" void kernel_launch(void* const* d_in, const int* in_sizes, int n_in,
                              void* d_out, int out_size, void* d_ws, size_t ws_size,
                              hipStream_t stream) {
    const float* hs    = (const float*)d_in[0];  // [4,4096,1024]
    const float* alpha = (const float*)d_in[1];  // [4,4]
    const float* dw    = (const float*)d_in[2];  // [4,16,1024]
    const float* uw    = (const float*)d_in[3];  // [4,1024,16]
    short* lowg = (short*)d_ws;                  // [16384][64] bf16 = 2 MB
    float* outp = (float*)d_out;

    hipLaunchKernelGGL(lora_low_k, dim3(256), dim3(512), 0, stream, hs, alpha, dw, lowg);
    hipLaunchKernelGGL(lora_up_k,  dim3(256), dim3(512), 0, stream, lowg, uw, outp);
}